// Round 7
// baseline (673.198 us; speedup 1.0000x reference)
//
#include <hip/hip_runtime.h>
#include <hip/hip_bf16.h>

#define NEG_SLOPE 0.2f

typedef __attribute__((ext_vector_type(8))) short bf16x8;
typedef __attribute__((ext_vector_type(4))) float f32x4;

static inline int cdiv(int a, int b) { return (a + b - 1) / b; }

__device__ inline unsigned short f2bf(float x) {
  __hip_bfloat16 b = __float2bfloat16(x);
  return *reinterpret_cast<unsigned short*>(&b);
}
__device__ inline float bf2f(unsigned short u) {
  unsigned int v = (unsigned int)u << 16;
  return *reinterpret_cast<float*>(&v);
}

// ---------------- h (f32) -> bf16 hi only ----------------
__global__ void split_hi_kernel(const float* __restrict__ x, unsigned short* __restrict__ hi, int n4) {
  int i = blockIdx.x * blockDim.x + threadIdx.x;
  if (i >= n4) return;
  float4 v = reinterpret_cast<const float4*>(x)[i];
  ushort4 hv; hv.x = f2bf(v.x); hv.y = f2bf(v.y); hv.z = f2bf(v.z); hv.w = f2bf(v.w);
  reinterpret_cast<ushort4*>(hi)[i] = hv;
}

// ---------------- split + transpose W[K][Mo] -> T[Mo][K] bf16 hi/lo ----------------
__global__ void splitT_kernel(const float* __restrict__ W, unsigned short* __restrict__ hi,
                              unsigned short* __restrict__ lo, int K, int Mo) {
  int i = blockIdx.x * blockDim.x + threadIdx.x;
  if (i >= K * Mo) return;
  int k = i / Mo, m = i - k * Mo;
  float v = W[i];
  unsigned short h = f2bf(v);
  hi[(size_t)m * K + k] = h;
  lo[(size_t)m * K + k] = f2bf(v - bf2f(h));
}

// ---------------- GEMM + fused attention-score partials; C written as bf16 hi ----------------
// Chi stored PHASE-MAJOR for the aggregate: Chi[(col>>5)][row][col&31] (slice = N*32 ushorts)
// 2-MFMA scheme: Ah·Bh + Ah·Bl (B = weights ~f32 via hi/lo; A single bf16 rounding)
template <int NF>
__global__ __launch_bounds__(256) void gemm_split(
    const unsigned short* __restrict__ Ahi,
    const unsigned short* __restrict__ BThi, const unsigned short* __restrict__ BTlo,
    unsigned short* __restrict__ Chi,
    const float* __restrict__ alv, const float* __restrict__ arv,
    float* __restrict__ el, float* __restrict__ er, int Hn, int M, int K, int Ncols) {
  constexpr int BN = NF * 32;
  __shared__ unsigned short As[128][40];   // hi at [0,32)
  __shared__ unsigned short Bs[BN][88];    // hi at [0,32), lo at [48,80)
  const int tid = threadIdx.x;
  const int row0 = blockIdx.x * 128;
  const int col0 = blockIdx.y * BN;
  const int wid = tid >> 6, lane = tid & 63;
  const int wm = wid >> 1, wn = wid & 1;
  const int l15 = lane & 15, lg = lane >> 4;
  f32x4 acc[4][NF];
#pragma unroll
  for (int m = 0; m < 4; ++m)
#pragma unroll
    for (int n = 0; n < NF; ++n) acc[m][n] = (f32x4){0.f, 0.f, 0.f, 0.f};

  const uint4 zero4 = {0u, 0u, 0u, 0u};
  for (int k0 = 0; k0 < K; k0 += 32) {
    {  // stage A (hi only)
      int r = tid >> 2;
      const int kg = tid & 3;
#pragma unroll
      for (int it = 0; it < 2; ++it, r += 64) {
        const int grow = row0 + r;
        uint4 vh = zero4;
        if (grow < M) vh = *reinterpret_cast<const uint4*>(&Ahi[(size_t)grow * K + k0 + kg * 8]);
        *reinterpret_cast<uint4*>(&As[r][kg * 8]) = vh;
      }
    }
    {  // stage B hi+lo
      int r = tid >> 2;
      const int kg = tid & 3;
#pragma unroll
      for (int it = 0; it < BN / 64; ++it, r += 64) {
        const int gcol = col0 + r;
        uint4 vh = *reinterpret_cast<const uint4*>(&BThi[(size_t)gcol * K + k0 + kg * 8]);
        uint4 vl = *reinterpret_cast<const uint4*>(&BTlo[(size_t)gcol * K + k0 + kg * 8]);
        *reinterpret_cast<uint4*>(&Bs[r][kg * 8]) = vh;
        *reinterpret_cast<uint4*>(&Bs[r][48 + kg * 8]) = vl;
      }
    }
    __syncthreads();
    bf16x8 ah[4];
#pragma unroll
    for (int m = 0; m < 4; ++m) {
      const int row = wm * 64 + m * 16 + l15;
      ah[m] = *reinterpret_cast<const bf16x8*>(&As[row][lg * 8]);
    }
#pragma unroll
    for (int n = 0; n < NF; ++n) {
      const int col = wn * (NF * 16) + n * 16 + l15;
      bf16x8 bh = *reinterpret_cast<const bf16x8*>(&Bs[col][lg * 8]);
      bf16x8 bl = *reinterpret_cast<const bf16x8*>(&Bs[col][48 + lg * 8]);
#pragma unroll
      for (int m = 0; m < 4; ++m) {
        acc[m][n] = __builtin_amdgcn_mfma_f32_16x16x32_bf16(ah[m], bh, acc[m][n], 0, 0, 0);
        acc[m][n] = __builtin_amdgcn_mfma_f32_16x16x32_bf16(ah[m], bl, acc[m][n], 0, 0, 0);
      }
    }
    __syncthreads();
  }
  // wave's NF col-frags all lie in one head (NF*16 <= 64)
  const int hw = (col0 + wn * (NF * 16)) >> 6;
  float alw[NF], arw[NF];
#pragma unroll
  for (int n = 0; n < NF; ++n) {
    const int colg = col0 + wn * (NF * 16) + n * 16 + l15;
    alw[n] = alv[colg];
    arw[n] = arv[colg];
  }
  float pel[4][4] = {{0.f}}, per_[4][4] = {{0.f}};
  // epilogue: C/D layout col=lane&15, row=(lane>>4)*4+j
#pragma unroll
  for (int m = 0; m < 4; ++m) {
#pragma unroll
    for (int n = 0; n < NF; ++n) {
      const int col = col0 + wn * (NF * 16) + n * 16 + l15;
      const size_t sliceBase = (size_t)(col >> 5) * M * 32 + (col & 31);
#pragma unroll
      for (int j = 0; j < 4; ++j) {
        const int row = row0 + wm * 64 + m * 16 + lg * 4 + j;
        const float v = acc[m][n][j];
        if (row < M) Chi[sliceBase + (size_t)row * 32] = f2bf(v);
        pel[m][j] = fmaf(v, alw[n], pel[m][j]);
        per_[m][j] = fmaf(v, arw[n], per_[m][j]);
      }
    }
  }
#pragma unroll
  for (int m = 0; m < 4; ++m) {
#pragma unroll
    for (int j = 0; j < 4; ++j) {
      float vl = pel[m][j], vr = per_[m][j];
#pragma unroll
      for (int off = 1; off < 16; off <<= 1) {
        vl += __shfl_xor(vl, off);
        vr += __shfl_xor(vr, off);
      }
      if (l15 == 0) {
        const int row = row0 + wm * 64 + m * 16 + lg * 4 + j;
        if (row < M) {
          atomicAdd(&el[(size_t)row * Hn + hw], vl);
          atomicAdd(&er[(size_t)row * Hn + hw], vr);
        }
      }
    }
  }
}

// ---------------- CSR build ----------------
__global__ void hist_kernel(const int* __restrict__ dst, int* __restrict__ deg, int E) {
  int i = blockIdx.x * blockDim.x + threadIdx.x;
  if (i < E) atomicAdd(&deg[dst[i]], 1);
}

__global__ void scan1(const int* __restrict__ deg, int* __restrict__ offs,
                      int* __restrict__ bsums, int N) {
  __shared__ int tmp[256];
  const int tid = threadIdx.x;
  const int i = blockIdx.x * 256 + tid;
  int v = (i < N) ? deg[i] : 0;
  tmp[tid] = v;
  __syncthreads();
  for (int d = 1; d < 256; d <<= 1) {
    int t = (tid >= d) ? tmp[tid - d] : 0;
    __syncthreads();
    tmp[tid] += t;
    __syncthreads();
  }
  if (i < N) offs[i] = tmp[tid] - v;
  if (tid == 255) bsums[blockIdx.x] = tmp[255];
}

__global__ void scan2(int* __restrict__ bsums, int nb) {
  __shared__ int tmp[256];
  const int tid = threadIdx.x;
  int v = (tid < nb) ? bsums[tid] : 0;
  tmp[tid] = v;
  __syncthreads();
  for (int d = 1; d < 256; d <<= 1) {
    int t = (tid >= d) ? tmp[tid - d] : 0;
    __syncthreads();
    tmp[tid] += t;
    __syncthreads();
  }
  if (tid < nb) bsums[tid] = tmp[tid] - v;
}

__global__ void scan3(int* __restrict__ offs, const int* __restrict__ bsums, int N, int E) {
  const int i = blockIdx.x * 256 + threadIdx.x;
  if (i < N) offs[i] += bsums[blockIdx.x];
  if (i == 0) offs[N] = E;
}

__global__ void scatter_kernel(const int* __restrict__ src, const int* __restrict__ dst,
                               const int* __restrict__ offs, int* __restrict__ cursor,
                               int* __restrict__ csr_src, int E) {
  int i = blockIdx.x * blockDim.x + threadIdx.x;
  if (i >= E) return;
  int dn = dst[i];
  int pos = atomicAdd(&cursor[dn], 1);
  csr_src[offs[dn] + pos] = src[i];
}

// ---------------- alpha: 16-lane group per dst node (4 nodes/wave) ----------------
template <int H>
__global__ void alpha16(const int* __restrict__ offs, const int* __restrict__ csr_src,
                        const float* __restrict__ el, const float* __restrict__ er,
                        float* __restrict__ abuf, int N) {
  const int w = (int)((blockIdx.x * (size_t)blockDim.x + threadIdx.x) >> 6);
  const int lane = threadIdx.x & 63;
  const int g = lane >> 4, q = lane & 15;
  const int node = w * 4 + g;
  int beg = 0, end = 0;
  float erh[H];
#pragma unroll
  for (int h = 0; h < H; ++h) erh[h] = 0.f;
  if (node < N) {
    beg = offs[node]; end = offs[node + 1];
    if constexpr (H == 4) {
      float4 t = *reinterpret_cast<const float4*>(&er[(size_t)node * 4]);
      erh[0] = t.x; erh[1] = t.y; erh[2] = t.z; erh[3] = t.w;
    } else {
      erh[0] = er[node];
    }
  }
  float m[H], s[H];
#pragma unroll
  for (int h = 0; h < H; ++h) { m[h] = -INFINITY; s[h] = 0.f; }
  for (int i0 = beg; i0 < end; i0 += 16) {
    const int i = i0 + q;
    const bool valid = i < end;
    const int sn = valid ? csr_src[i] : 0;
    float e[H];
    if constexpr (H == 4) {
      float4 v = *reinterpret_cast<const float4*>(&el[(size_t)sn * 4]);
      e[0] = v.x + erh[0]; e[1] = v.y + erh[1]; e[2] = v.z + erh[2]; e[3] = v.w + erh[3];
    } else {
      e[0] = el[sn] + erh[0];
    }
#pragma unroll
    for (int h = 0; h < H; ++h) {
      e[h] = e[h] > 0.f ? e[h] : NEG_SLOPE * e[h];
      if (!valid) e[h] = -INFINITY;
      float cm = e[h];
#pragma unroll
      for (int off = 1; off < 16; off <<= 1) cm = fmaxf(cm, __shfl_xor(cm, off));
      const float nm = fmaxf(m[h], cm);
      float cs = __expf(e[h] - nm);
#pragma unroll
      for (int off = 1; off < 16; off <<= 1) cs += __shfl_xor(cs, off);
      s[h] = s[h] * __expf(m[h] - nm) + cs;
      m[h] = nm;
    }
  }
  float inv[H];
#pragma unroll
  for (int h = 0; h < H; ++h) inv[h] = 1.f / fmaxf(s[h], 1e-9f);
  for (int i0 = beg; i0 < end; i0 += 16) {
    const int i = i0 + q;
    if (i < end) {
      const int sn = csr_src[i];
      float e[H];
      if constexpr (H == 4) {
        float4 v = *reinterpret_cast<const float4*>(&el[(size_t)sn * 4]);
        e[0] = v.x + erh[0]; e[1] = v.y + erh[1]; e[2] = v.z + erh[2]; e[3] = v.w + erh[3];
      } else {
        e[0] = el[sn] + erh[0];
      }
#pragma unroll
      for (int h = 0; h < H; ++h) {
        e[h] = e[h] > 0.f ? e[h] : NEG_SLOPE * e[h];
        e[h] = __expf(e[h] - m[h]) * inv[h];
      }
      if constexpr (H == 4) {
        float4 o; o.x = e[0]; o.y = e[1]; o.z = e[2]; o.w = e[3];
        *reinterpret_cast<float4*>(&abuf[(size_t)i * 4]) = o;
      } else {
        abuf[i] = e[0];
      }
    }
  }
}

// ---------------- phased aggregate H=4: blockIdx.y = phase p = h*2+half ----------------
// slice p holds [node][32] bf16 (3.2 MB, fits one XCD L2). Wave = node; lane: f=lane&31,
// edge-parity group g=lane>>5. Output col = (p>>1)*64 + (p&1)*32 + f, written bf16 (next layer A).
__global__ void aggregate_h4p(const int* __restrict__ offs, const int* __restrict__ csr_src,
                              const unsigned short* __restrict__ slices, const float* __restrict__ abuf,
                              const float* __restrict__ bias, unsigned short* __restrict__ outhi,
                              int N) {
  const int p = blockIdx.y;
  const int h = p >> 1;
  const int node = (int)((blockIdx.x * (size_t)blockDim.x + threadIdx.x) >> 6);
  const int lane = threadIdx.x & 63;
  const int f = lane & 31, g = lane >> 5;
  if (node >= N) return;
  const int beg = offs[node], end = offs[node + 1];
  const unsigned short* __restrict__ slice = slices + (size_t)p * N * 32;
  float acc = 0.f;
  int i = beg + g;
  for (; i + 6 < end; i += 8) {
    const int s0 = csr_src[i], s1 = csr_src[i + 2], s2 = csr_src[i + 4], s3 = csr_src[i + 6];
    const float a0 = abuf[(size_t)i * 4 + h];
    const float a1 = abuf[(size_t)(i + 2) * 4 + h];
    const float a2 = abuf[(size_t)(i + 4) * 4 + h];
    const float a3 = abuf[(size_t)(i + 6) * 4 + h];
    const unsigned short u0 = slice[(size_t)s0 * 32 + f];
    const unsigned short u1 = slice[(size_t)s1 * 32 + f];
    const unsigned short u2 = slice[(size_t)s2 * 32 + f];
    const unsigned short u3 = slice[(size_t)s3 * 32 + f];
    acc = fmaf(a0, bf2f(u0), acc);
    acc = fmaf(a1, bf2f(u1), acc);
    acc = fmaf(a2, bf2f(u2), acc);
    acc = fmaf(a3, bf2f(u3), acc);
  }
  for (; i < end; i += 2) {
    const int sn = csr_src[i];
    const float a = abuf[(size_t)i * 4 + h];
    acc = fmaf(a, bf2f(slice[(size_t)sn * 32 + f]), acc);
  }
  acc += __shfl_xor(acc, 32);
  if (g == 0) {
    const int col = h * 64 + (p & 1) * 32 + f;
    outhi[(size_t)node * 256 + col] = f2bf(acc + bias[col]);
  }
}

// ---------------- phased aggregate H=1: blockIdx.y = phase p (half) ----------------
__global__ void aggregate1p(const int* __restrict__ offs, const int* __restrict__ csr_src,
                            const unsigned short* __restrict__ slices, const float* __restrict__ abuf,
                            const float* __restrict__ bias, float* __restrict__ outf, int N) {
  const int p = blockIdx.y;
  const int node = (int)((blockIdx.x * (size_t)blockDim.x + threadIdx.x) >> 6);
  const int lane = threadIdx.x & 63;
  const int f = lane & 31, g = lane >> 5;
  if (node >= N) return;
  const int beg = offs[node], end = offs[node + 1];
  const unsigned short* __restrict__ slice = slices + (size_t)p * N * 32;
  float acc = 0.f;
  int i = beg + g;
  for (; i + 6 < end; i += 8) {
    const int s0 = csr_src[i], s1 = csr_src[i + 2], s2 = csr_src[i + 4], s3 = csr_src[i + 6];
    const float a0 = abuf[i], a1 = abuf[i + 2], a2 = abuf[i + 4], a3 = abuf[i + 6];
    const unsigned short u0 = slice[(size_t)s0 * 32 + f];
    const unsigned short u1 = slice[(size_t)s1 * 32 + f];
    const unsigned short u2 = slice[(size_t)s2 * 32 + f];
    const unsigned short u3 = slice[(size_t)s3 * 32 + f];
    acc = fmaf(a0, bf2f(u0), acc);
    acc = fmaf(a1, bf2f(u1), acc);
    acc = fmaf(a2, bf2f(u2), acc);
    acc = fmaf(a3, bf2f(u3), acc);
  }
  for (; i < end; i += 2) {
    acc = fmaf(abuf[i], bf2f(slice[(size_t)csr_src[i] * 32 + f]), acc);
  }
  acc += __shfl_xor(acc, 32);
  if (g == 0) {
    const int col = p * 32 + f;
    outf[(size_t)node * 64 + col] = acc + bias[col];
  }
}

// ---------------- tail: ids as float ----------------
__global__ void copy_ids(const int* __restrict__ ids, float* __restrict__ out, int n) {
  int i = blockIdx.x * blockDim.x + threadIdx.x;
  if (i < n) out[i] = (float)ids[i];
}

extern "C" void kernel_launch(void* const* d_in, const int* in_sizes, int n_in,
                              void* d_out, int out_size, void* d_ws, size_t ws_size,
                              hipStream_t stream) {
  const float* h   = (const float*)d_in[0];
  const int* src   = (const int*)d_in[1];
  const int* dst   = (const int*)d_in[2];
  const int* ids   = (const int*)d_in[3];
  const float* W0  = (const float*)d_in[4];
  const float* al0 = (const float*)d_in[5];
  const float* ar0 = (const float*)d_in[6];
  const float* b0  = (const float*)d_in[7];
  const float* W1  = (const float*)d_in[8];
  const float* al1 = (const float*)d_in[9];
  const float* ar1 = (const float*)d_in[10];
  const float* b1  = (const float*)d_in[11];
  const float* W2  = (const float*)d_in[12];
  const float* al2 = (const float*)d_in[13];
  const float* ar2 = (const float*)d_in[14];
  const float* b2  = (const float*)d_in[15];

  const int Din = 256, HF = 256, F2 = 64;
  const int N = in_sizes[0] / Din;        // 50000
  const int E = in_sizes[1];              // 800000
  const int NIDS = in_sizes[3];           // 1024

  // workspace layout (16B-aligned chunks)
  char* p = (char*)d_ws;
  unsigned short* Chi = (unsigned short*)p; p += (size_t)N * 256 * 2;  // feat bf16, phase-major
  unsigned short* Ahi = (unsigned short*)p; p += (size_t)N * 256 * 2;  // GEMM input, row-major
  unsigned short* W0hi = (unsigned short*)p; p += (size_t)HF * Din * 2;
  unsigned short* W0lo = (unsigned short*)p; p += (size_t)HF * Din * 2;
  unsigned short* W1hi = (unsigned short*)p; p += (size_t)HF * HF * 2;
  unsigned short* W1lo = (unsigned short*)p; p += (size_t)HF * HF * 2;
  unsigned short* W2hi = (unsigned short*)p; p += (size_t)F2 * HF * 2;
  unsigned short* W2lo = (unsigned short*)p; p += (size_t)F2 * HF * 2;
  float* el   = (float*)p;             p += (size_t)N * 4 * 4;
  float* er   = (float*)p;             p += (size_t)N * 4 * 4;
  float* abuf = (float*)p;             p += (size_t)E * 4 * 4;
  int* deg    = (int*)p;               p += (size_t)N * 4;
  int* offs   = (int*)p;               p += (size_t)(N + 16) * 4;
  int* bsums  = (int*)p;               p += 256 * 4;
  int* csr_src = (int*)p;              p += (size_t)E * 4;

  float* outp = (float*)d_out;
  dim3 blk(256);
  const int nb = cdiv(N, 256);
  const int nwAlpha = cdiv(cdiv(N, 4) * 64, 256);
  const int nbAgg = cdiv(N, 4);          // 4 nodes (waves) per block

  // ---------------- pre-passes: splits ----------------
  split_hi_kernel<<<cdiv(N * 256 / 4, 256), blk, 0, stream>>>(h, Ahi, N * 256 / 4);
  splitT_kernel<<<cdiv(Din * HF, 256), blk, 0, stream>>>(W0, W0hi, W0lo, Din, HF);
  splitT_kernel<<<cdiv(HF * HF, 256), blk, 0, stream>>>(W1, W1hi, W1lo, HF, HF);
  splitT_kernel<<<cdiv(HF * F2, 256), blk, 0, stream>>>(W2, W2hi, W2lo, HF, F2);

  // ---------------- CSR build (shared by all 3 layers) ----------------
  hipMemsetAsync(deg, 0, (size_t)N * 4, stream);
  hist_kernel<<<cdiv(E, 256), blk, 0, stream>>>(dst, deg, E);
  scan1<<<nb, blk, 0, stream>>>(deg, offs, bsums, N);
  scan2<<<1, blk, 0, stream>>>(bsums, nb);
  scan3<<<nb, blk, 0, stream>>>(offs, bsums, N, E);
  hipMemsetAsync(deg, 0, (size_t)N * 4, stream);
  scatter_kernel<<<cdiv(E, 256), blk, 0, stream>>>(src, dst, offs, deg, csr_src, E);

  // ---------------- layer 0 (H=4): Ahi -> Chi(phase-major) -> Ahi ----------------
  {
    hipMemsetAsync(el, 0, (size_t)N * 4 * 4 * 2, stream);   // el+er contiguous
    dim3 g(cdiv(N, 128), HF / 128);
    gemm_split<4><<<g, blk, 0, stream>>>(Ahi, W0hi, W0lo, Chi, al0, ar0, el, er, 4, N, Din, HF);
    alpha16<4><<<nwAlpha, blk, 0, stream>>>(offs, csr_src, el, er, abuf, N);
    aggregate_h4p<<<dim3(nbAgg, 8), blk, 0, stream>>>(offs, csr_src, Chi, abuf, b0, Ahi, N);
  }
  // ---------------- layer 1 (H=4) ----------------
  {
    hipMemsetAsync(el, 0, (size_t)N * 4 * 4 * 2, stream);
    dim3 g(cdiv(N, 128), HF / 128);
    gemm_split<4><<<g, blk, 0, stream>>>(Ahi, W1hi, W1lo, Chi, al1, ar1, el, er, 4, N, HF, HF);
    alpha16<4><<<nwAlpha, blk, 0, stream>>>(offs, csr_src, el, er, abuf, N);
    aggregate_h4p<<<dim3(nbAgg, 8), blk, 0, stream>>>(offs, csr_src, Chi, abuf, b1, Ahi, N);
  }
  // ---------------- layer 2 (H=1): -> d_out ----------------
  {
    hipMemsetAsync(el, 0, (size_t)N * 4 * 4 * 2, stream);
    dim3 g(cdiv(N, 128), 1);
    gemm_split<2><<<g, blk, 0, stream>>>(Ahi, W2hi, W2lo, Chi, al2, ar2, el, er, 1, N, HF, F2);
    alpha16<1><<<nwAlpha, blk, 0, stream>>>(offs, csr_src, el, er, abuf, N);
    aggregate1p<<<dim3(nbAgg, 2), blk, 0, stream>>>(offs, csr_src, Chi, abuf, b2, outp, N);
  }
  // ---------------- tail ids ----------------
  copy_ids<<<cdiv(NIDS, 256), blk, 0, stream>>>(ids, outp + (size_t)N * F2, NIDS);
}

// Round 8
// 501.301 us; speedup vs baseline: 1.3429x; 1.3429x over previous
//
#include <hip/hip_runtime.h>
#include <hip/hip_bf16.h>

#define NEG_SLOPE 0.2f

typedef __attribute__((ext_vector_type(8))) short bf16x8;
typedef __attribute__((ext_vector_type(4))) float f32x4;

static inline int cdiv(int a, int b) { return (a + b - 1) / b; }

__device__ inline unsigned short f2bf(float x) {
  __hip_bfloat16 b = __float2bfloat16(x);
  return *reinterpret_cast<unsigned short*>(&b);
}
__device__ inline float bf2f(unsigned short u) {
  unsigned int v = (unsigned int)u << 16;
  return *reinterpret_cast<float*>(&v);
}

// ---------------- h (f32) -> bf16 hi only ----------------
__global__ void split_hi_kernel(const float* __restrict__ x, unsigned short* __restrict__ hi, int n4) {
  int i = blockIdx.x * blockDim.x + threadIdx.x;
  if (i >= n4) return;
  float4 v = reinterpret_cast<const float4*>(x)[i];
  ushort4 hv; hv.x = f2bf(v.x); hv.y = f2bf(v.y); hv.z = f2bf(v.z); hv.w = f2bf(v.w);
  reinterpret_cast<ushort4*>(hi)[i] = hv;
}

// ---------------- split + transpose W[K][Mo] -> T[Mo][K] bf16 hi/lo ----------------
__global__ void splitT_kernel(const float* __restrict__ W, unsigned short* __restrict__ hi,
                              unsigned short* __restrict__ lo, int K, int Mo) {
  int i = blockIdx.x * blockDim.x + threadIdx.x;
  if (i >= K * Mo) return;
  int k = i / Mo, m = i - k * Mo;
  float v = W[i];
  unsigned short h = f2bf(v);
  hi[(size_t)m * K + k] = h;
  lo[(size_t)m * K + k] = f2bf(v - bf2f(h));
}

// ---------------- GEMM + fused attention-score partials; C written as bf16 hi ----------------
// Chi[M][Ncols] = Ah[M][K] @ (BThi+BTlo)[Ncols][K]^T ; el/er += C·al / C·ar (atomic)
// 2-MFMA scheme: Ah·Bh + Ah·Bl (B = weights ~f32 via hi/lo; A single bf16 rounding)
template <int NF>
__global__ __launch_bounds__(256) void gemm_split(
    const unsigned short* __restrict__ Ahi,
    const unsigned short* __restrict__ BThi, const unsigned short* __restrict__ BTlo,
    unsigned short* __restrict__ Chi,
    const float* __restrict__ alv, const float* __restrict__ arv,
    float* __restrict__ el, float* __restrict__ er, int Hn, int M, int K, int Ncols) {
  constexpr int BN = NF * 32;
  __shared__ unsigned short As[128][40];   // hi at [0,32)
  __shared__ unsigned short Bs[BN][88];    // hi at [0,32), lo at [48,80)
  const int tid = threadIdx.x;
  const int row0 = blockIdx.x * 128;
  const int col0 = blockIdx.y * BN;
  const int wid = tid >> 6, lane = tid & 63;
  const int wm = wid >> 1, wn = wid & 1;
  const int l15 = lane & 15, lg = lane >> 4;
  f32x4 acc[4][NF];
#pragma unroll
  for (int m = 0; m < 4; ++m)
#pragma unroll
    for (int n = 0; n < NF; ++n) acc[m][n] = (f32x4){0.f, 0.f, 0.f, 0.f};

  const uint4 zero4 = {0u, 0u, 0u, 0u};
  for (int k0 = 0; k0 < K; k0 += 32) {
    {  // stage A (hi only)
      int r = tid >> 2;
      const int kg = tid & 3;
#pragma unroll
      for (int it = 0; it < 2; ++it, r += 64) {
        const int grow = row0 + r;
        uint4 vh = zero4;
        if (grow < M) vh = *reinterpret_cast<const uint4*>(&Ahi[(size_t)grow * K + k0 + kg * 8]);
        *reinterpret_cast<uint4*>(&As[r][kg * 8]) = vh;
      }
    }
    {  // stage B hi+lo
      int r = tid >> 2;
      const int kg = tid & 3;
#pragma unroll
      for (int it = 0; it < BN / 64; ++it, r += 64) {
        const int gcol = col0 + r;
        uint4 vh = *reinterpret_cast<const uint4*>(&BThi[(size_t)gcol * K + k0 + kg * 8]);
        uint4 vl = *reinterpret_cast<const uint4*>(&BTlo[(size_t)gcol * K + k0 + kg * 8]);
        *reinterpret_cast<uint4*>(&Bs[r][kg * 8]) = vh;
        *reinterpret_cast<uint4*>(&Bs[r][48 + kg * 8]) = vl;
      }
    }
    __syncthreads();
    bf16x8 ah[4];
#pragma unroll
    for (int m = 0; m < 4; ++m) {
      const int row = wm * 64 + m * 16 + l15;
      ah[m] = *reinterpret_cast<const bf16x8*>(&As[row][lg * 8]);
    }
#pragma unroll
    for (int n = 0; n < NF; ++n) {
      const int col = wn * (NF * 16) + n * 16 + l15;
      bf16x8 bh = *reinterpret_cast<const bf16x8*>(&Bs[col][lg * 8]);
      bf16x8 bl = *reinterpret_cast<const bf16x8*>(&Bs[col][48 + lg * 8]);
#pragma unroll
      for (int m = 0; m < 4; ++m) {
        acc[m][n] = __builtin_amdgcn_mfma_f32_16x16x32_bf16(ah[m], bh, acc[m][n], 0, 0, 0);
        acc[m][n] = __builtin_amdgcn_mfma_f32_16x16x32_bf16(ah[m], bl, acc[m][n], 0, 0, 0);
      }
    }
    __syncthreads();
  }
  // wave's NF col-frags all lie in one head (NF*16 <= 64)
  const int hw = (col0 + wn * (NF * 16)) >> 6;
  float alw[NF], arw[NF];
#pragma unroll
  for (int n = 0; n < NF; ++n) {
    const int colg = col0 + wn * (NF * 16) + n * 16 + l15;
    alw[n] = alv[colg];
    arw[n] = arv[colg];
  }
  float pel[4][4] = {{0.f}}, per_[4][4] = {{0.f}};
  // epilogue: C/D layout col=lane&15, row=(lane>>4)*4+j
#pragma unroll
  for (int m = 0; m < 4; ++m) {
#pragma unroll
    for (int n = 0; n < NF; ++n) {
      const int col = col0 + wn * (NF * 16) + n * 16 + l15;
#pragma unroll
      for (int j = 0; j < 4; ++j) {
        const int row = row0 + wm * 64 + m * 16 + lg * 4 + j;
        const float v = acc[m][n][j];
        if (row < M) Chi[(size_t)row * Ncols + col] = f2bf(v);
        pel[m][j] = fmaf(v, alw[n], pel[m][j]);
        per_[m][j] = fmaf(v, arw[n], per_[m][j]);
      }
    }
  }
#pragma unroll
  for (int m = 0; m < 4; ++m) {
#pragma unroll
    for (int j = 0; j < 4; ++j) {
      float vl = pel[m][j], vr = per_[m][j];
#pragma unroll
      for (int off = 1; off < 16; off <<= 1) {
        vl += __shfl_xor(vl, off);
        vr += __shfl_xor(vr, off);
      }
      if (l15 == 0) {
        const int row = row0 + wm * 64 + m * 16 + lg * 4 + j;
        if (row < M) {
          atomicAdd(&el[(size_t)row * Hn + hw], vl);
          atomicAdd(&er[(size_t)row * Hn + hw], vr);
        }
      }
    }
  }
}

// ---------------- CSR build ----------------
__global__ void hist_kernel(const int* __restrict__ dst, int* __restrict__ deg, int E) {
  int i = blockIdx.x * blockDim.x + threadIdx.x;
  if (i < E) atomicAdd(&deg[dst[i]], 1);
}

__global__ void scan1(const int* __restrict__ deg, int* __restrict__ offs,
                      int* __restrict__ bsums, int N) {
  __shared__ int tmp[256];
  const int tid = threadIdx.x;
  const int i = blockIdx.x * 256 + tid;
  int v = (i < N) ? deg[i] : 0;
  tmp[tid] = v;
  __syncthreads();
  for (int d = 1; d < 256; d <<= 1) {
    int t = (tid >= d) ? tmp[tid - d] : 0;
    __syncthreads();
    tmp[tid] += t;
    __syncthreads();
  }
  if (i < N) offs[i] = tmp[tid] - v;
  if (tid == 255) bsums[blockIdx.x] = tmp[255];
}

__global__ void scan2(int* __restrict__ bsums, int nb) {
  __shared__ int tmp[256];
  const int tid = threadIdx.x;
  int v = (tid < nb) ? bsums[tid] : 0;
  tmp[tid] = v;
  __syncthreads();
  for (int d = 1; d < 256; d <<= 1) {
    int t = (tid >= d) ? tmp[tid - d] : 0;
    __syncthreads();
    tmp[tid] += t;
    __syncthreads();
  }
  if (tid < nb) bsums[tid] = tmp[tid] - v;
}

__global__ void scan3(int* __restrict__ offs, const int* __restrict__ bsums, int N, int E) {
  const int i = blockIdx.x * 256 + threadIdx.x;
  if (i < N) offs[i] += bsums[blockIdx.x];
  if (i == 0) offs[N] = E;
}

__global__ void scatter_kernel(const int* __restrict__ src, const int* __restrict__ dst,
                               const int* __restrict__ offs, int* __restrict__ cursor,
                               int* __restrict__ csr_src, int E) {
  int i = blockIdx.x * blockDim.x + threadIdx.x;
  if (i >= E) return;
  int dn = dst[i];
  int pos = atomicAdd(&cursor[dn], 1);
  csr_src[offs[dn] + pos] = src[i];
}

// ---------------- alpha: 16-lane group per dst node (4 nodes/wave) ----------------
template <int H>
__global__ void alpha16(const int* __restrict__ offs, const int* __restrict__ csr_src,
                        const float* __restrict__ el, const float* __restrict__ er,
                        float* __restrict__ abuf, int N) {
  const int w = (int)((blockIdx.x * (size_t)blockDim.x + threadIdx.x) >> 6);
  const int lane = threadIdx.x & 63;
  const int g = lane >> 4, q = lane & 15;
  const int node = w * 4 + g;
  int beg = 0, end = 0;
  float erh[H];
#pragma unroll
  for (int h = 0; h < H; ++h) erh[h] = 0.f;
  if (node < N) {
    beg = offs[node]; end = offs[node + 1];
    if constexpr (H == 4) {
      float4 t = *reinterpret_cast<const float4*>(&er[(size_t)node * 4]);
      erh[0] = t.x; erh[1] = t.y; erh[2] = t.z; erh[3] = t.w;
    } else {
      erh[0] = er[node];
    }
  }
  float m[H], s[H];
#pragma unroll
  for (int h = 0; h < H; ++h) { m[h] = -INFINITY; s[h] = 0.f; }
  for (int i0 = beg; i0 < end; i0 += 16) {
    const int i = i0 + q;
    const bool valid = i < end;
    const int sn = valid ? csr_src[i] : 0;
    float e[H];
    if constexpr (H == 4) {
      float4 v = *reinterpret_cast<const float4*>(&el[(size_t)sn * 4]);
      e[0] = v.x + erh[0]; e[1] = v.y + erh[1]; e[2] = v.z + erh[2]; e[3] = v.w + erh[3];
    } else {
      e[0] = el[sn] + erh[0];
    }
#pragma unroll
    for (int h = 0; h < H; ++h) {
      e[h] = e[h] > 0.f ? e[h] : NEG_SLOPE * e[h];
      if (!valid) e[h] = -INFINITY;
      float cm = e[h];
#pragma unroll
      for (int off = 1; off < 16; off <<= 1) cm = fmaxf(cm, __shfl_xor(cm, off));
      const float nm = fmaxf(m[h], cm);
      float cs = __expf(e[h] - nm);
#pragma unroll
      for (int off = 1; off < 16; off <<= 1) cs += __shfl_xor(cs, off);
      s[h] = s[h] * __expf(m[h] - nm) + cs;
      m[h] = nm;
    }
  }
  float inv[H];
#pragma unroll
  for (int h = 0; h < H; ++h) inv[h] = 1.f / fmaxf(s[h], 1e-9f);
  for (int i0 = beg; i0 < end; i0 += 16) {
    const int i = i0 + q;
    if (i < end) {
      const int sn = csr_src[i];
      float e[H];
      if constexpr (H == 4) {
        float4 v = *reinterpret_cast<const float4*>(&el[(size_t)sn * 4]);
        e[0] = v.x + erh[0]; e[1] = v.y + erh[1]; e[2] = v.z + erh[2]; e[3] = v.w + erh[3];
      } else {
        e[0] = el[sn] + erh[0];
      }
#pragma unroll
      for (int h = 0; h < H; ++h) {
        e[h] = e[h] > 0.f ? e[h] : NEG_SLOPE * e[h];
        e[h] = __expf(e[h] - m[h]) * inv[h];
      }
      if constexpr (H == 4) {
        float4 o; o.x = e[0]; o.y = e[1]; o.z = e[2]; o.w = e[3];
        *reinterpret_cast<float4*>(&abuf[(size_t)i * 4]) = o;
      } else {
        abuf[i] = e[0];
      }
    }
  }
}

// ---------------- aggregate H=4: TWO waves per node (2 heads each), bf16 gather, 8-edge unroll ----------------
// wave w: node = w>>1, head-pair hp = w&1 (heads 2hp, 2hp+1). lane owns features
// hp*128+lane and hp*128+64+lane. Doubles wave count vs R6 for latency hiding.
template <bool SPLIT>
__global__ void aggregate_h4(const int* __restrict__ offs, const int* __restrict__ csr_src,
                             const unsigned short* __restrict__ featH, const float2* __restrict__ abuf2,
                             const float* __restrict__ bias, float* __restrict__ outf,
                             unsigned short* __restrict__ outhi, int N) {
  const int w = (int)((blockIdx.x * (size_t)blockDim.x + threadIdx.x) >> 6);
  const int lane = threadIdx.x & 63;
  const int node = w >> 1, hp = w & 1;
  if (node >= N) return;
  const int beg = offs[node], end = offs[node + 1];
  const int fb = hp * 128 + lane;
  float a0 = 0.f, a1 = 0.f;
  int i = beg;
  for (; i + 7 < end; i += 8) {
    int sn[8]; float2 av[8];
    unsigned short u0[8], u1[8];
#pragma unroll
    for (int u = 0; u < 8; ++u) sn[u] = csr_src[i + u];
#pragma unroll
    for (int u = 0; u < 8; ++u) av[u] = abuf2[(size_t)(i + u) * 2 + hp];
#pragma unroll
    for (int u = 0; u < 8; ++u) {
      const unsigned short* f = &featH[(size_t)sn[u] * 256 + fb];
      u0[u] = f[0]; u1[u] = f[64];
    }
#pragma unroll
    for (int u = 0; u < 8; ++u) {
      a0 = fmaf(av[u].x, bf2f(u0[u]), a0);
      a1 = fmaf(av[u].y, bf2f(u1[u]), a1);
    }
  }
  for (; i < end; ++i) {
    const int sn = csr_src[i];
    const float2 av = abuf2[(size_t)i * 2 + hp];
    const unsigned short* f = &featH[(size_t)sn * 256 + fb];
    a0 = fmaf(av.x, bf2f(f[0]), a0);
    a1 = fmaf(av.y, bf2f(f[64]), a1);
  }
  const float o0 = a0 + bias[fb];
  const float o1 = a1 + bias[fb + 64];
  const size_t base = (size_t)node * 256 + fb;
  if constexpr (SPLIT) {
    outhi[base] = f2bf(o0);
    outhi[base + 64] = f2bf(o1);
  } else {
    outf[base] = o0;
    outf[base + 64] = o1;
  }
}

// ---------------- aggregate H=1: 16-lane groups, 4 edges/iter, bf16 gather ----------------
__global__ void aggregate1(const int* __restrict__ offs, const int* __restrict__ csr_src,
                           const unsigned short* __restrict__ featH, const float* __restrict__ abuf,
                           const float* __restrict__ bias, float* __restrict__ outf, int N) {
  const int wid = (int)((blockIdx.x * (size_t)blockDim.x + threadIdx.x) >> 6);
  const int lane = threadIdx.x & 63;
  if (wid >= N) return;
  const int beg = offs[wid], end = offs[wid + 1];
  const int g = lane >> 4, q = lane & 15;
  float4 acc = make_float4(0.f, 0.f, 0.f, 0.f);
  for (int i0 = beg; i0 < end; i0 += 4) {
    const int e = i0 + g;
    if (e < end) {
      const int sn = csr_src[e];
      const float a = abuf[e];
      const ushort4 u = *reinterpret_cast<const ushort4*>(&featH[(size_t)sn * 64 + q * 4]);
      acc.x = fmaf(a, bf2f(u.x), acc.x);
      acc.y = fmaf(a, bf2f(u.y), acc.y);
      acc.z = fmaf(a, bf2f(u.z), acc.z);
      acc.w = fmaf(a, bf2f(u.w), acc.w);
    }
  }
#pragma unroll
  for (int off = 16; off <= 32; off <<= 1) {
    acc.x += __shfl_xor(acc.x, off);
    acc.y += __shfl_xor(acc.y, off);
    acc.z += __shfl_xor(acc.z, off);
    acc.w += __shfl_xor(acc.w, off);
  }
  if (lane < 16) {
    const float4 b4 = *reinterpret_cast<const float4*>(&bias[q * 4]);
    float4 o = make_float4(acc.x + b4.x, acc.y + b4.y, acc.z + b4.z, acc.w + b4.w);
    *reinterpret_cast<float4*>(&outf[(size_t)wid * 64 + q * 4]) = o;
  }
}

// ---------------- tail: ids as float ----------------
__global__ void copy_ids(const int* __restrict__ ids, float* __restrict__ out, int n) {
  int i = blockIdx.x * blockDim.x + threadIdx.x;
  if (i < n) out[i] = (float)ids[i];
}

extern "C" void kernel_launch(void* const* d_in, const int* in_sizes, int n_in,
                              void* d_out, int out_size, void* d_ws, size_t ws_size,
                              hipStream_t stream) {
  const float* h   = (const float*)d_in[0];
  const int* src   = (const int*)d_in[1];
  const int* dst   = (const int*)d_in[2];
  const int* ids   = (const int*)d_in[3];
  const float* W0  = (const float*)d_in[4];
  const float* al0 = (const float*)d_in[5];
  const float* ar0 = (const float*)d_in[6];
  const float* b0  = (const float*)d_in[7];
  const float* W1  = (const float*)d_in[8];
  const float* al1 = (const float*)d_in[9];
  const float* ar1 = (const float*)d_in[10];
  const float* b1  = (const float*)d_in[11];
  const float* W2  = (const float*)d_in[12];
  const float* al2 = (const float*)d_in[13];
  const float* ar2 = (const float*)d_in[14];
  const float* b2  = (const float*)d_in[15];

  const int Din = 256, HF = 256, F2 = 64;
  const int N = in_sizes[0] / Din;        // 50000
  const int E = in_sizes[1];              // 800000
  const int NIDS = in_sizes[3];           // 1024

  // workspace layout (16B-aligned chunks)
  char* p = (char*)d_ws;
  unsigned short* Chi = (unsigned short*)p; p += (size_t)N * 256 * 2;  // feat bf16 hi
  unsigned short* Ahi = (unsigned short*)p; p += (size_t)N * 256 * 2;  // GEMM input hi
  unsigned short* W0hi = (unsigned short*)p; p += (size_t)HF * Din * 2;
  unsigned short* W0lo = (unsigned short*)p; p += (size_t)HF * Din * 2;
  unsigned short* W1hi = (unsigned short*)p; p += (size_t)HF * HF * 2;
  unsigned short* W1lo = (unsigned short*)p; p += (size_t)HF * HF * 2;
  unsigned short* W2hi = (unsigned short*)p; p += (size_t)F2 * HF * 2;
  unsigned short* W2lo = (unsigned short*)p; p += (size_t)F2 * HF * 2;
  float* el   = (float*)p;             p += (size_t)N * 4 * 4;
  float* er   = (float*)p;             p += (size_t)N * 4 * 4;
  float* abuf = (float*)p;             p += (size_t)E * 4 * 4;
  int* deg    = (int*)p;               p += (size_t)N * 4;
  int* offs   = (int*)p;               p += (size_t)(N + 16) * 4;
  int* bsums  = (int*)p;               p += 256 * 4;
  int* csr_src = (int*)p;              p += (size_t)E * 4;

  float* outp = (float*)d_out;
  dim3 blk(256);
  const int nb = cdiv(N, 256);
  const int nwAlpha = cdiv(cdiv(N, 4) * 64, 256);
  const int nbAggH4 = cdiv(N * 2 * 64, 256);   // 2 waves per node

  // ---------------- pre-passes: splits ----------------
  split_hi_kernel<<<cdiv(N * 256 / 4, 256), blk, 0, stream>>>(h, Ahi, N * 256 / 4);
  splitT_kernel<<<cdiv(Din * HF, 256), blk, 0, stream>>>(W0, W0hi, W0lo, Din, HF);
  splitT_kernel<<<cdiv(HF * HF, 256), blk, 0, stream>>>(W1, W1hi, W1lo, HF, HF);
  splitT_kernel<<<cdiv(HF * F2, 256), blk, 0, stream>>>(W2, W2hi, W2lo, HF, F2);

  // ---------------- CSR build (shared by all 3 layers) ----------------
  hipMemsetAsync(deg, 0, (size_t)N * 4, stream);
  hist_kernel<<<cdiv(E, 256), blk, 0, stream>>>(dst, deg, E);
  scan1<<<nb, blk, 0, stream>>>(deg, offs, bsums, N);
  scan2<<<1, blk, 0, stream>>>(bsums, nb);
  scan3<<<nb, blk, 0, stream>>>(offs, bsums, N, E);
  hipMemsetAsync(deg, 0, (size_t)N * 4, stream);
  scatter_kernel<<<cdiv(E, 256), blk, 0, stream>>>(src, dst, offs, deg, csr_src, E);

  // ---------------- layer 0 (H=4): Ahi -> Chi -> Ahi ----------------
  {
    hipMemsetAsync(el, 0, (size_t)N * 4 * 4 * 2, stream);   // el+er contiguous
    dim3 g(cdiv(N, 128), HF / 128);
    gemm_split<4><<<g, blk, 0, stream>>>(Ahi, W0hi, W0lo, Chi, al0, ar0, el, er, 4, N, Din, HF);
    alpha16<4><<<nwAlpha, blk, 0, stream>>>(offs, csr_src, el, er, abuf, N);
    aggregate_h4<true><<<nbAggH4, blk, 0, stream>>>(offs, csr_src, Chi, (const float2*)abuf,
                                                    b0, nullptr, Ahi, N);
  }
  // ---------------- layer 1 (H=4) ----------------
  {
    hipMemsetAsync(el, 0, (size_t)N * 4 * 4 * 2, stream);
    dim3 g(cdiv(N, 128), HF / 128);
    gemm_split<4><<<g, blk, 0, stream>>>(Ahi, W1hi, W1lo, Chi, al1, ar1, el, er, 4, N, HF, HF);
    alpha16<4><<<nwAlpha, blk, 0, stream>>>(offs, csr_src, el, er, abuf, N);
    aggregate_h4<true><<<nbAggH4, blk, 0, stream>>>(offs, csr_src, Chi, (const float2*)abuf,
                                                    b1, nullptr, Ahi, N);
  }
  // ---------------- layer 2 (H=1): -> d_out ----------------
  {
    hipMemsetAsync(el, 0, (size_t)N * 4 * 4 * 2, stream);
    dim3 g(cdiv(N, 128), 1);
    gemm_split<2><<<g, blk, 0, stream>>>(Ahi, W2hi, W2lo, Chi, al2, ar2, el, er, 1, N, HF, F2);
    alpha16<1><<<nwAlpha, blk, 0, stream>>>(offs, csr_src, el, er, abuf, N);
    aggregate1<<<cdiv(N * 64, 256), blk, 0, stream>>>(offs, csr_src, Chi, abuf, b2, outp, N);
  }
  // ---------------- tail ids ----------------
  copy_ids<<<cdiv(NIDS, 256), blk, 0, stream>>>(ids, outp + (size_t)N * F2, NIDS);
}

// Round 9
// 414.995 us; speedup vs baseline: 1.6222x; 1.2080x over previous
//
#include <hip/hip_runtime.h>
#include <hip/hip_bf16.h>

#define NEG_SLOPE 0.2f

typedef __attribute__((ext_vector_type(8))) short bf16x8;
typedef __attribute__((ext_vector_type(4))) float f32x4;

static inline int cdiv(int a, int b) { return (a + b - 1) / b; }

__device__ inline unsigned short f2bf(float x) {
  __hip_bfloat16 b = __float2bfloat16(x);
  return *reinterpret_cast<unsigned short*>(&b);
}
__device__ inline float bf2f(unsigned short u) {
  unsigned int v = (unsigned int)u << 16;
  return *reinterpret_cast<float*>(&v);
}

// ---------------- h (f32) -> bf16 hi only ----------------
__global__ void split_hi_kernel(const float* __restrict__ x, unsigned short* __restrict__ hi, int n4) {
  int i = blockIdx.x * blockDim.x + threadIdx.x;
  if (i >= n4) return;
  float4 v = reinterpret_cast<const float4*>(x)[i];
  ushort4 hv; hv.x = f2bf(v.x); hv.y = f2bf(v.y); hv.z = f2bf(v.z); hv.w = f2bf(v.w);
  reinterpret_cast<ushort4*>(hi)[i] = hv;
}

// ---------------- split + transpose W[K][Mo] -> T[Mo][K] bf16 hi/lo ----------------
// permK: apply k-index permutation pi(k) = (k&63)*4 + (k>>6) to match interleaved A layout
__global__ void splitT_kernel(const float* __restrict__ W, unsigned short* __restrict__ hi,
                              unsigned short* __restrict__ lo, int K, int Mo, int permK) {
  int i = blockIdx.x * blockDim.x + threadIdx.x;
  if (i >= K * Mo) return;
  int k = i / Mo, m = i - k * Mo;
  int kk = permK ? ((k & 63) * 4 + (k >> 6)) : k;
  float v = W[i];
  unsigned short h = f2bf(v);
  hi[(size_t)m * K + kk] = h;
  lo[(size_t)m * K + kk] = f2bf(v - bf2f(h));
}

// ---------------- GEMM + fused attention-score partials; C written as bf16 hi ----------------
// 2-MFMA scheme: Ah·Bh + Ah·Bl. For NF=4: Chi written HEAD-INTERLEAVED
// (Chi[row*256 + (col&63)*4 + (col>>6)]), el/er written by PLAIN STORE (one
// contributor per (row,head)). For NF=2: standard layout, atomic el/er.
template <int NF>
__global__ __launch_bounds__(256) void gemm_split(
    const unsigned short* __restrict__ Ahi,
    const unsigned short* __restrict__ BThi, const unsigned short* __restrict__ BTlo,
    unsigned short* __restrict__ Chi,
    const float* __restrict__ alv, const float* __restrict__ arv,
    float* __restrict__ el, float* __restrict__ er, int Hn, int M, int K, int Ncols) {
  constexpr int BN = NF * 32;
  __shared__ unsigned short As[128][40];   // hi at [0,32)
  __shared__ unsigned short Bs[BN][88];    // hi at [0,32), lo at [48,80)
  const int tid = threadIdx.x;
  const int row0 = blockIdx.x * 128;
  const int col0 = blockIdx.y * BN;
  const int wid = tid >> 6, lane = tid & 63;
  const int wm = wid >> 1, wn = wid & 1;
  const int l15 = lane & 15, lg = lane >> 4;
  f32x4 acc[4][NF];
#pragma unroll
  for (int m = 0; m < 4; ++m)
#pragma unroll
    for (int n = 0; n < NF; ++n) acc[m][n] = (f32x4){0.f, 0.f, 0.f, 0.f};

  const uint4 zero4 = {0u, 0u, 0u, 0u};
  for (int k0 = 0; k0 < K; k0 += 32) {
    {  // stage A (hi only)
      int r = tid >> 2;
      const int kg = tid & 3;
#pragma unroll
      for (int it = 0; it < 2; ++it, r += 64) {
        const int grow = row0 + r;
        uint4 vh = zero4;
        if (grow < M) vh = *reinterpret_cast<const uint4*>(&Ahi[(size_t)grow * K + k0 + kg * 8]);
        *reinterpret_cast<uint4*>(&As[r][kg * 8]) = vh;
      }
    }
    {  // stage B hi+lo
      int r = tid >> 2;
      const int kg = tid & 3;
#pragma unroll
      for (int it = 0; it < BN / 64; ++it, r += 64) {
        const int gcol = col0 + r;
        uint4 vh = *reinterpret_cast<const uint4*>(&BThi[(size_t)gcol * K + k0 + kg * 8]);
        uint4 vl = *reinterpret_cast<const uint4*>(&BTlo[(size_t)gcol * K + k0 + kg * 8]);
        *reinterpret_cast<uint4*>(&Bs[r][kg * 8]) = vh;
        *reinterpret_cast<uint4*>(&Bs[r][48 + kg * 8]) = vl;
      }
    }
    __syncthreads();
    bf16x8 ah[4];
#pragma unroll
    for (int m = 0; m < 4; ++m) {
      const int row = wm * 64 + m * 16 + l15;
      ah[m] = *reinterpret_cast<const bf16x8*>(&As[row][lg * 8]);
    }
#pragma unroll
    for (int n = 0; n < NF; ++n) {
      const int col = wn * (NF * 16) + n * 16 + l15;
      bf16x8 bh = *reinterpret_cast<const bf16x8*>(&Bs[col][lg * 8]);
      bf16x8 bl = *reinterpret_cast<const bf16x8*>(&Bs[col][48 + lg * 8]);
#pragma unroll
      for (int m = 0; m < 4; ++m) {
        acc[m][n] = __builtin_amdgcn_mfma_f32_16x16x32_bf16(ah[m], bh, acc[m][n], 0, 0, 0);
        acc[m][n] = __builtin_amdgcn_mfma_f32_16x16x32_bf16(ah[m], bl, acc[m][n], 0, 0, 0);
      }
    }
    __syncthreads();
  }
  // wave's NF col-frags all lie in one head (NF*16 <= 64)
  const int hw = (col0 + wn * (NF * 16)) >> 6;
  float alw[NF], arw[NF];
#pragma unroll
  for (int n = 0; n < NF; ++n) {
    const int colg = col0 + wn * (NF * 16) + n * 16 + l15;
    alw[n] = alv[colg];
    arw[n] = arv[colg];
  }
  float pel[4][4] = {{0.f}}, per_[4][4] = {{0.f}};
  // epilogue: C/D layout col=lane&15, row=(lane>>4)*4+j
#pragma unroll
  for (int m = 0; m < 4; ++m) {
#pragma unroll
    for (int n = 0; n < NF; ++n) {
      const int col = col0 + wn * (NF * 16) + n * 16 + l15;
#pragma unroll
      for (int j = 0; j < 4; ++j) {
        const int row = row0 + wm * 64 + m * 16 + lg * 4 + j;
        const float v = acc[m][n][j];
        if (row < M) {
          if constexpr (NF == 4) {
            Chi[(size_t)row * 256 + (col & 63) * 4 + (col >> 6)] = f2bf(v);  // interleaved
          } else {
            Chi[(size_t)row * Ncols + col] = f2bf(v);
          }
        }
        pel[m][j] = fmaf(v, alw[n], pel[m][j]);
        per_[m][j] = fmaf(v, arw[n], per_[m][j]);
      }
    }
  }
#pragma unroll
  for (int m = 0; m < 4; ++m) {
#pragma unroll
    for (int j = 0; j < 4; ++j) {
      float vl = pel[m][j], vr = per_[m][j];
#pragma unroll
      for (int off = 1; off < 16; off <<= 1) {
        vl += __shfl_xor(vl, off);
        vr += __shfl_xor(vr, off);
      }
      if (l15 == 0) {
        const int row = row0 + wm * 64 + m * 16 + lg * 4 + j;
        if (row < M) {
          if constexpr (NF == 4) {  // exactly one contributor per (row,head)
            el[(size_t)row * Hn + hw] = vl;
            er[(size_t)row * Hn + hw] = vr;
          } else {
            atomicAdd(&el[(size_t)row * Hn + hw], vl);
            atomicAdd(&er[(size_t)row * Hn + hw], vr);
          }
        }
      }
    }
  }
}

// ---------------- CSR build ----------------
__global__ void hist_kernel(const int* __restrict__ dst, int* __restrict__ deg, int E) {
  int i = blockIdx.x * blockDim.x + threadIdx.x;
  if (i < E) atomicAdd(&deg[dst[i]], 1);
}

__global__ void scan1(const int* __restrict__ deg, int* __restrict__ offs,
                      int* __restrict__ bsums, int N) {
  __shared__ int tmp[256];
  const int tid = threadIdx.x;
  const int i = blockIdx.x * 256 + tid;
  int v = (i < N) ? deg[i] : 0;
  tmp[tid] = v;
  __syncthreads();
  for (int d = 1; d < 256; d <<= 1) {
    int t = (tid >= d) ? tmp[tid - d] : 0;
    __syncthreads();
    tmp[tid] += t;
    __syncthreads();
  }
  if (i < N) offs[i] = tmp[tid] - v;
  if (tid == 255) bsums[blockIdx.x] = tmp[255];
}

__global__ void scan2(int* __restrict__ bsums, int nb) {
  __shared__ int tmp[256];
  const int tid = threadIdx.x;
  int v = (tid < nb) ? bsums[tid] : 0;
  tmp[tid] = v;
  __syncthreads();
  for (int d = 1; d < 256; d <<= 1) {
    int t = (tid >= d) ? tmp[tid - d] : 0;
    __syncthreads();
    tmp[tid] += t;
    __syncthreads();
  }
  if (tid < nb) bsums[tid] = tmp[tid] - v;
}

__global__ void scan3(int* __restrict__ offs, const int* __restrict__ bsums, int N, int E) {
  const int i = blockIdx.x * 256 + threadIdx.x;
  if (i < N) offs[i] += bsums[blockIdx.x];
  if (i == 0) offs[N] = E;
}

__global__ void scatter_kernel(const int* __restrict__ src, const int* __restrict__ dst,
                               const int* __restrict__ offs, int* __restrict__ cursor,
                               int* __restrict__ csr_src, int E) {
  int i = blockIdx.x * blockDim.x + threadIdx.x;
  if (i >= E) return;
  int dn = dst[i];
  int pos = atomicAdd(&cursor[dn], 1);
  csr_src[offs[dn] + pos] = src[i];
}

// ---------------- alpha: 16-lane group per dst node (4 nodes/wave) ----------------
template <int H>
__global__ void alpha16(const int* __restrict__ offs, const int* __restrict__ csr_src,
                        const float* __restrict__ el, const float* __restrict__ er,
                        float* __restrict__ abuf, int N) {
  const int w = (int)((blockIdx.x * (size_t)blockDim.x + threadIdx.x) >> 6);
  const int lane = threadIdx.x & 63;
  const int g = lane >> 4, q = lane & 15;
  const int node = w * 4 + g;
  int beg = 0, end = 0;
  float erh[H];
#pragma unroll
  for (int h = 0; h < H; ++h) erh[h] = 0.f;
  if (node < N) {
    beg = offs[node]; end = offs[node + 1];
    if constexpr (H == 4) {
      float4 t = *reinterpret_cast<const float4*>(&er[(size_t)node * 4]);
      erh[0] = t.x; erh[1] = t.y; erh[2] = t.z; erh[3] = t.w;
    } else {
      erh[0] = er[node];
    }
  }
  float m[H], s[H];
#pragma unroll
  for (int h = 0; h < H; ++h) { m[h] = -INFINITY; s[h] = 0.f; }
  for (int i0 = beg; i0 < end; i0 += 16) {
    const int i = i0 + q;
    const bool valid = i < end;
    const int sn = valid ? csr_src[i] : 0;
    float e[H];
    if constexpr (H == 4) {
      float4 v = *reinterpret_cast<const float4*>(&el[(size_t)sn * 4]);
      e[0] = v.x + erh[0]; e[1] = v.y + erh[1]; e[2] = v.z + erh[2]; e[3] = v.w + erh[3];
    } else {
      e[0] = el[sn] + erh[0];
    }
#pragma unroll
    for (int h = 0; h < H; ++h) {
      e[h] = e[h] > 0.f ? e[h] : NEG_SLOPE * e[h];
      if (!valid) e[h] = -INFINITY;
      float cm = e[h];
#pragma unroll
      for (int off = 1; off < 16; off <<= 1) cm = fmaxf(cm, __shfl_xor(cm, off));
      const float nm = fmaxf(m[h], cm);
      float cs = __expf(e[h] - nm);
#pragma unroll
      for (int off = 1; off < 16; off <<= 1) cs += __shfl_xor(cs, off);
      s[h] = s[h] * __expf(m[h] - nm) + cs;
      m[h] = nm;
    }
  }
  float inv[H];
#pragma unroll
  for (int h = 0; h < H; ++h) inv[h] = 1.f / fmaxf(s[h], 1e-9f);
  for (int i0 = beg; i0 < end; i0 += 16) {
    const int i = i0 + q;
    if (i < end) {
      const int sn = csr_src[i];
      float e[H];
      if constexpr (H == 4) {
        float4 v = *reinterpret_cast<const float4*>(&el[(size_t)sn * 4]);
        e[0] = v.x + erh[0]; e[1] = v.y + erh[1]; e[2] = v.z + erh[2]; e[3] = v.w + erh[3];
      } else {
        e[0] = el[sn] + erh[0];
      }
#pragma unroll
      for (int h = 0; h < H; ++h) {
        e[h] = e[h] > 0.f ? e[h] : NEG_SLOPE * e[h];
        e[h] = __expf(e[h] - m[h]) * inv[h];
      }
      if constexpr (H == 4) {
        float4 o; o.x = e[0]; o.y = e[1]; o.z = e[2]; o.w = e[3];
        *reinterpret_cast<float4*>(&abuf[(size_t)i * 4]) = o;
      } else {
        abuf[i] = e[0];
      }
    }
  }
}

// ---------------- aggregate H=4: one wave/node, HEAD-INTERLEAVED ushort4 gather, 8-edge unroll ----------------
// feat layout: [node][f=0..63][h=0..3] bf16. Lane owns feature f=lane (all 4 heads).
// One 8B load per edge per lane. Output written interleaved ushort4 (next layer A, k-permuted).
__global__ void aggregate_h4(const int* __restrict__ offs, const int* __restrict__ csr_src,
                             const ushort4* __restrict__ feat4, const float4* __restrict__ abuf,
                             const float* __restrict__ bias, ushort4* __restrict__ out4, int N) {
  const int node = (int)((blockIdx.x * (size_t)blockDim.x + threadIdx.x) >> 6);
  const int lane = threadIdx.x & 63;
  if (node >= N) return;
  const int beg = offs[node], end = offs[node + 1];
  float a0 = 0.f, a1 = 0.f, a2 = 0.f, a3 = 0.f;
  int i = beg;
  for (; i + 7 < end; i += 8) {
    int sn[8]; float4 w[8]; ushort4 uv[8];
#pragma unroll
    for (int u = 0; u < 8; ++u) sn[u] = csr_src[i + u];
#pragma unroll
    for (int u = 0; u < 8; ++u) w[u] = abuf[i + u];
#pragma unroll
    for (int u = 0; u < 8; ++u) uv[u] = feat4[(size_t)sn[u] * 64 + lane];
#pragma unroll
    for (int u = 0; u < 8; ++u) {
      a0 = fmaf(w[u].x, bf2f(uv[u].x), a0);
      a1 = fmaf(w[u].y, bf2f(uv[u].y), a1);
      a2 = fmaf(w[u].z, bf2f(uv[u].z), a2);
      a3 = fmaf(w[u].w, bf2f(uv[u].w), a3);
    }
  }
  for (; i < end; ++i) {
    const int sn = csr_src[i];
    const float4 w = abuf[i];
    const ushort4 uv = feat4[(size_t)sn * 64 + lane];
    a0 = fmaf(w.x, bf2f(uv.x), a0);
    a1 = fmaf(w.y, bf2f(uv.y), a1);
    a2 = fmaf(w.z, bf2f(uv.z), a2);
    a3 = fmaf(w.w, bf2f(uv.w), a3);
  }
  const float o0 = a0 + bias[lane];
  const float o1 = a1 + bias[64 + lane];
  const float o2 = a2 + bias[128 + lane];
  const float o3 = a3 + bias[192 + lane];
  ushort4 ov;
  ov.x = f2bf(o0); ov.y = f2bf(o1); ov.z = f2bf(o2); ov.w = f2bf(o3);
  out4[(size_t)node * 64 + lane] = ov;
}

// ---------------- aggregate H=1: 16-lane groups, 4 edges/iter, bf16 gather (standard layout) ----------------
__global__ void aggregate1(const int* __restrict__ offs, const int* __restrict__ csr_src,
                           const unsigned short* __restrict__ featH, const float* __restrict__ abuf,
                           const float* __restrict__ bias, float* __restrict__ outf, int N) {
  const int wid = (int)((blockIdx.x * (size_t)blockDim.x + threadIdx.x) >> 6);
  const int lane = threadIdx.x & 63;
  if (wid >= N) return;
  const int beg = offs[wid], end = offs[wid + 1];
  const int g = lane >> 4, q = lane & 15;
  float4 acc = make_float4(0.f, 0.f, 0.f, 0.f);
  for (int i0 = beg; i0 < end; i0 += 4) {
    const int e = i0 + g;
    if (e < end) {
      const int sn = csr_src[e];
      const float a = abuf[e];
      const ushort4 u = *reinterpret_cast<const ushort4*>(&featH[(size_t)sn * 64 + q * 4]);
      acc.x = fmaf(a, bf2f(u.x), acc.x);
      acc.y = fmaf(a, bf2f(u.y), acc.y);
      acc.z = fmaf(a, bf2f(u.z), acc.z);
      acc.w = fmaf(a, bf2f(u.w), acc.w);
    }
  }
#pragma unroll
  for (int off = 16; off <= 32; off <<= 1) {
    acc.x += __shfl_xor(acc.x, off);
    acc.y += __shfl_xor(acc.y, off);
    acc.z += __shfl_xor(acc.z, off);
    acc.w += __shfl_xor(acc.w, off);
  }
  if (lane < 16) {
    const float4 b4 = *reinterpret_cast<const float4*>(&bias[q * 4]);
    float4 o = make_float4(acc.x + b4.x, acc.y + b4.y, acc.z + b4.z, acc.w + b4.w);
    *reinterpret_cast<float4*>(&outf[(size_t)wid * 64 + q * 4]) = o;
  }
}

// ---------------- tail: ids as float ----------------
__global__ void copy_ids(const int* __restrict__ ids, float* __restrict__ out, int n) {
  int i = blockIdx.x * blockDim.x + threadIdx.x;
  if (i < n) out[i] = (float)ids[i];
}

extern "C" void kernel_launch(void* const* d_in, const int* in_sizes, int n_in,
                              void* d_out, int out_size, void* d_ws, size_t ws_size,
                              hipStream_t stream) {
  const float* h   = (const float*)d_in[0];
  const int* src   = (const int*)d_in[1];
  const int* dst   = (const int*)d_in[2];
  const int* ids   = (const int*)d_in[3];
  const float* W0  = (const float*)d_in[4];
  const float* al0 = (const float*)d_in[5];
  const float* ar0 = (const float*)d_in[6];
  const float* b0  = (const float*)d_in[7];
  const float* W1  = (const float*)d_in[8];
  const float* al1 = (const float*)d_in[9];
  const float* ar1 = (const float*)d_in[10];
  const float* b1  = (const float*)d_in[11];
  const float* W2  = (const float*)d_in[12];
  const float* al2 = (const float*)d_in[13];
  const float* ar2 = (const float*)d_in[14];
  const float* b2  = (const float*)d_in[15];

  const int Din = 256, HF = 256, F2 = 64;
  const int N = in_sizes[0] / Din;        // 50000
  const int E = in_sizes[1];              // 800000
  const int NIDS = in_sizes[3];           // 1024

  // workspace layout (16B-aligned chunks)
  char* p = (char*)d_ws;
  unsigned short* Chi = (unsigned short*)p; p += (size_t)N * 256 * 2;  // feat bf16 (interleaved for H=4)
  unsigned short* Ahi = (unsigned short*)p; p += (size_t)N * 256 * 2;  // GEMM input
  unsigned short* W0hi = (unsigned short*)p; p += (size_t)HF * Din * 2;
  unsigned short* W0lo = (unsigned short*)p; p += (size_t)HF * Din * 2;
  unsigned short* W1hi = (unsigned short*)p; p += (size_t)HF * HF * 2;
  unsigned short* W1lo = (unsigned short*)p; p += (size_t)HF * HF * 2;
  unsigned short* W2hi = (unsigned short*)p; p += (size_t)F2 * HF * 2;
  unsigned short* W2lo = (unsigned short*)p; p += (size_t)F2 * HF * 2;
  float* el   = (float*)p;             p += (size_t)N * 4 * 4;
  float* er   = (float*)p;             p += (size_t)N * 4 * 4;
  float* abuf = (float*)p;             p += (size_t)E * 4 * 4;
  int* deg    = (int*)p;               p += (size_t)N * 4;
  int* offs   = (int*)p;               p += (size_t)(N + 16) * 4;
  int* bsums  = (int*)p;               p += 256 * 4;
  int* csr_src = (int*)p;              p += (size_t)E * 4;

  float* outp = (float*)d_out;
  dim3 blk(256);
  const int nb = cdiv(N, 256);
  const int nwAlpha = cdiv(cdiv(N, 4) * 64, 256);

  // ---------------- pre-passes: splits (W1/W2 K-permuted to match interleaved A) ----------------
  split_hi_kernel<<<cdiv(N * 256 / 4, 256), blk, 0, stream>>>(h, Ahi, N * 256 / 4);
  splitT_kernel<<<cdiv(Din * HF, 256), blk, 0, stream>>>(W0, W0hi, W0lo, Din, HF, 0);
  splitT_kernel<<<cdiv(HF * HF, 256), blk, 0, stream>>>(W1, W1hi, W1lo, HF, HF, 1);
  splitT_kernel<<<cdiv(HF * F2, 256), blk, 0, stream>>>(W2, W2hi, W2lo, HF, F2, 1);

  // ---------------- CSR build (shared by all 3 layers) ----------------
  hipMemsetAsync(deg, 0, (size_t)N * 4, stream);
  hist_kernel<<<cdiv(E, 256), blk, 0, stream>>>(dst, deg, E);
  scan1<<<nb, blk, 0, stream>>>(deg, offs, bsums, N);
  scan2<<<1, blk, 0, stream>>>(bsums, nb);
  scan3<<<nb, blk, 0, stream>>>(offs, bsums, N, E);
  hipMemsetAsync(deg, 0, (size_t)N * 4, stream);
  scatter_kernel<<<cdiv(E, 256), blk, 0, stream>>>(src, dst, offs, deg, csr_src, E);

  // ---------------- layer 0 (H=4): Ahi -> Chi(interleaved) -> Ahi(interleaved) ----------------
  {
    dim3 g(cdiv(N, 128), HF / 128);
    gemm_split<4><<<g, blk, 0, stream>>>(Ahi, W0hi, W0lo, Chi, al0, ar0, el, er, 4, N, Din, HF);
    alpha16<4><<<nwAlpha, blk, 0, stream>>>(offs, csr_src, el, er, abuf, N);
    aggregate_h4<<<cdiv(N * 64, 256), blk, 0, stream>>>(offs, csr_src, (const ushort4*)Chi,
                                                        (const float4*)abuf, b0, (ushort4*)Ahi, N);
  }
  // ---------------- layer 1 (H=4) ----------------
  {
    dim3 g(cdiv(N, 128), HF / 128);
    gemm_split<4><<<g, blk, 0, stream>>>(Ahi, W1hi, W1lo, Chi, al1, ar1, el, er, 4, N, HF, HF);
    alpha16<4><<<nwAlpha, blk, 0, stream>>>(offs, csr_src, el, er, abuf, N);
    aggregate_h4<<<cdiv(N * 64, 256), blk, 0, stream>>>(offs, csr_src, (const ushort4*)Chi,
                                                        (const float4*)abuf, b1, (ushort4*)Ahi, N);
  }
  // ---------------- layer 2 (H=1): -> d_out (standard layout) ----------------
  {
    hipMemsetAsync(el, 0, (size_t)N * 4, stream);
    hipMemsetAsync(er, 0, (size_t)N * 4, stream);
    dim3 g(cdiv(N, 128), 1);
    gemm_split<2><<<g, blk, 0, stream>>>(Ahi, W2hi, W2lo, Chi, al2, ar2, el, er, 1, N, HF, F2);
    alpha16<1><<<nwAlpha, blk, 0, stream>>>(offs, csr_src, el, er, abuf, N);
    aggregate1<<<cdiv(N * 64, 256), blk, 0, stream>>>(offs, csr_src, Chi, abuf, b2, outp, N);
  }
  // ---------------- tail ids ----------------
  copy_ids<<<cdiv(NIDS, 256), blk, 0, stream>>>(ids, outp + (size_t)N * F2, NIDS);
}

// Round 10
// 401.352 us; speedup vs baseline: 1.6773x; 1.0340x over previous
//
#include <hip/hip_runtime.h>
#include <hip/hip_bf16.h>

#define NEG_SLOPE 0.2f

typedef __attribute__((ext_vector_type(8))) short bf16x8;
typedef __attribute__((ext_vector_type(4))) float f32x4;

static inline int cdiv(int a, int b) { return (a + b - 1) / b; }

__device__ inline unsigned short f2bf(float x) {
  __hip_bfloat16 b = __float2bfloat16(x);
  return *reinterpret_cast<unsigned short*>(&b);
}
__device__ inline float bf2f(unsigned short u) {
  unsigned int v = (unsigned int)u << 16;
  return *reinterpret_cast<float*>(&v);
}

// ---------------- fused split+transpose for all 3 weights ----------------
// W[K][Mo] -> T[Mo][K] bf16 hi/lo; W1/W2 get k-permutation pi(k)=(k&63)*4+(k>>6)
__global__ void splitT_all(const float* __restrict__ W0, unsigned short* __restrict__ W0hi,
                           unsigned short* __restrict__ W0lo,
                           const float* __restrict__ W1, unsigned short* __restrict__ W1hi,
                           unsigned short* __restrict__ W1lo,
                           const float* __restrict__ W2, unsigned short* __restrict__ W2hi,
                           unsigned short* __restrict__ W2lo) {
  const int S0 = 256 * 256, S1 = 256 * 256, S2 = 256 * 64;
  int i = blockIdx.x * blockDim.x + threadIdx.x;
  const float* W; unsigned short *hi, *lo; int K, Mo, perm;
  if (i < S0) { W = W0; hi = W0hi; lo = W0lo; K = 256; Mo = 256; perm = 0; }
  else if (i < S0 + S1) { i -= S0; W = W1; hi = W1hi; lo = W1lo; K = 256; Mo = 256; perm = 1; }
  else if (i < S0 + S1 + S2) { i -= S0 + S1; W = W2; hi = W2hi; lo = W2lo; K = 256; Mo = 64; perm = 1; }
  else return;
  int k = i / Mo, m = i - k * Mo;
  int kk = perm ? ((k & 63) * 4 + (k >> 6)) : k;
  float v = W[i];
  unsigned short h = f2bf(v);
  hi[(size_t)m * K + kk] = h;
  lo[(size_t)m * K + kk] = f2bf(v - bf2f(h));
}

// ---------------- GEMM + fused attention-score partials; C written as bf16 hi ----------------
// 2-MFMA scheme: Ah·Bh + Ah·Bl. CVT: stage A from f32 source (converting).
// NF=4: Chi HEAD-INTERLEAVED (row*256 + (col&63)*4 + (col>>6)), el/er plain store.
// NF=2: Chi standard, el/er via cross-wave LDS reduce + plain store (no memset needed).
template <int NF, bool CVT>
__global__ __launch_bounds__(256) void gemm_split(
    const unsigned short* __restrict__ Ahi, const float* __restrict__ Af32,
    const unsigned short* __restrict__ BThi, const unsigned short* __restrict__ BTlo,
    unsigned short* __restrict__ Chi,
    const float* __restrict__ alv, const float* __restrict__ arv,
    float* __restrict__ el, float* __restrict__ er, int Hn, int M, int K, int Ncols) {
  constexpr int BN = NF * 32;
  __shared__ unsigned short As[128][40];   // hi at [0,32)
  __shared__ unsigned short Bs[BN][88];    // hi at [0,32), lo at [48,80)
  const int tid = threadIdx.x;
  const int row0 = blockIdx.x * 128;
  const int col0 = blockIdx.y * BN;
  const int wid = tid >> 6, lane = tid & 63;
  const int wm = wid >> 1, wn = wid & 1;
  const int l15 = lane & 15, lg = lane >> 4;
  f32x4 acc[4][NF];
#pragma unroll
  for (int m = 0; m < 4; ++m)
#pragma unroll
    for (int n = 0; n < NF; ++n) acc[m][n] = (f32x4){0.f, 0.f, 0.f, 0.f};

  const uint4 zero4 = {0u, 0u, 0u, 0u};
  for (int k0 = 0; k0 < K; k0 += 32) {
    {  // stage A (hi only)
      int r = tid >> 2;
      const int kg = tid & 3;
#pragma unroll
      for (int it = 0; it < 2; ++it, r += 64) {
        const int grow = row0 + r;
        if constexpr (CVT) {
          float4 f0 = make_float4(0.f, 0.f, 0.f, 0.f), f1 = f0;
          if (grow < M) {
            f0 = *reinterpret_cast<const float4*>(&Af32[(size_t)grow * K + k0 + kg * 8]);
            f1 = *reinterpret_cast<const float4*>(&Af32[(size_t)grow * K + k0 + kg * 8 + 4]);
          }
          unsigned short t[8];
          t[0] = f2bf(f0.x); t[1] = f2bf(f0.y); t[2] = f2bf(f0.z); t[3] = f2bf(f0.w);
          t[4] = f2bf(f1.x); t[5] = f2bf(f1.y); t[6] = f2bf(f1.z); t[7] = f2bf(f1.w);
          *reinterpret_cast<uint4*>(&As[r][kg * 8]) = *reinterpret_cast<const uint4*>(t);
        } else {
          uint4 vh = zero4;
          if (grow < M) vh = *reinterpret_cast<const uint4*>(&Ahi[(size_t)grow * K + k0 + kg * 8]);
          *reinterpret_cast<uint4*>(&As[r][kg * 8]) = vh;
        }
      }
    }
    {  // stage B hi+lo
      int r = tid >> 2;
      const int kg = tid & 3;
#pragma unroll
      for (int it = 0; it < BN / 64; ++it, r += 64) {
        const int gcol = col0 + r;
        uint4 vh = *reinterpret_cast<const uint4*>(&BThi[(size_t)gcol * K + k0 + kg * 8]);
        uint4 vl = *reinterpret_cast<const uint4*>(&BTlo[(size_t)gcol * K + k0 + kg * 8]);
        *reinterpret_cast<uint4*>(&Bs[r][kg * 8]) = vh;
        *reinterpret_cast<uint4*>(&Bs[r][48 + kg * 8]) = vl;
      }
    }
    __syncthreads();
    bf16x8 ah[4];
#pragma unroll
    for (int m = 0; m < 4; ++m) {
      const int row = wm * 64 + m * 16 + l15;
      ah[m] = *reinterpret_cast<const bf16x8*>(&As[row][lg * 8]);
    }
#pragma unroll
    for (int n = 0; n < NF; ++n) {
      const int col = wn * (NF * 16) + n * 16 + l15;
      bf16x8 bh = *reinterpret_cast<const bf16x8*>(&Bs[col][lg * 8]);
      bf16x8 bl = *reinterpret_cast<const bf16x8*>(&Bs[col][48 + lg * 8]);
#pragma unroll
      for (int m = 0; m < 4; ++m) {
        acc[m][n] = __builtin_amdgcn_mfma_f32_16x16x32_bf16(ah[m], bh, acc[m][n], 0, 0, 0);
        acc[m][n] = __builtin_amdgcn_mfma_f32_16x16x32_bf16(ah[m], bl, acc[m][n], 0, 0, 0);
      }
    }
    __syncthreads();
  }
  // wave's NF col-frags all lie in one head (NF*16 <= 64)
  const int hw = (col0 + wn * (NF * 16)) >> 6;
  float alw[NF], arw[NF];
#pragma unroll
  for (int n = 0; n < NF; ++n) {
    const int colg = col0 + wn * (NF * 16) + n * 16 + l15;
    alw[n] = alv[colg];
    arw[n] = arv[colg];
  }
  float pel[4][4] = {{0.f}}, per_[4][4] = {{0.f}};
  // epilogue: C/D layout col=lane&15, row=(lane>>4)*4+j
#pragma unroll
  for (int m = 0; m < 4; ++m) {
#pragma unroll
    for (int n = 0; n < NF; ++n) {
      const int col = col0 + wn * (NF * 16) + n * 16 + l15;
#pragma unroll
      for (int j = 0; j < 4; ++j) {
        const int row = row0 + wm * 64 + m * 16 + lg * 4 + j;
        const float v = acc[m][n][j];
        if (row < M) {
          if constexpr (NF == 4) {
            Chi[(size_t)row * 256 + (col & 63) * 4 + (col >> 6)] = f2bf(v);  // interleaved
          } else {
            Chi[(size_t)row * Ncols + col] = f2bf(v);
          }
        }
        pel[m][j] = fmaf(v, alw[n], pel[m][j]);
        per_[m][j] = fmaf(v, arw[n], per_[m][j]);
      }
    }
  }
  float rl[4][4], rr[4][4];
#pragma unroll
  for (int m = 0; m < 4; ++m) {
#pragma unroll
    for (int j = 0; j < 4; ++j) {
      float vl = pel[m][j], vr = per_[m][j];
#pragma unroll
      for (int off = 1; off < 16; off <<= 1) {
        vl += __shfl_xor(vl, off);
        vr += __shfl_xor(vr, off);
      }
      rl[m][j] = vl; rr[m][j] = vr;
    }
  }
  if constexpr (NF == 4) {
    if (l15 == 0) {
#pragma unroll
      for (int m = 0; m < 4; ++m)
#pragma unroll
        for (int j = 0; j < 4; ++j) {
          const int row = row0 + wm * 64 + m * 16 + lg * 4 + j;
          if (row < M) {
            el[(size_t)row * 4 + hw] = rl[m][j];
            er[(size_t)row * 4 + hw] = rr[m][j];
          }
        }
    }
  } else {
    __shared__ float sl[128], sr[128];
    if (wn == 1 && l15 == 0) {
#pragma unroll
      for (int m = 0; m < 4; ++m)
#pragma unroll
        for (int j = 0; j < 4; ++j) {
          const int lr = wm * 64 + m * 16 + lg * 4 + j;
          sl[lr] = rl[m][j]; sr[lr] = rr[m][j];
        }
    }
    __syncthreads();
    if (wn == 0 && l15 == 0) {
#pragma unroll
      for (int m = 0; m < 4; ++m)
#pragma unroll
        for (int j = 0; j < 4; ++j) {
          const int lr = wm * 64 + m * 16 + lg * 4 + j;
          const int row = row0 + lr;
          if (row < M) {
            el[row] = rl[m][j] + sl[lr];
            er[row] = rr[m][j] + sr[lr];
          }
        }
    }
  }
}

// ---------------- CSR build ----------------
__global__ void hist_kernel(const int* __restrict__ dst, int* __restrict__ deg, int E) {
  int i = blockIdx.x * blockDim.x + threadIdx.x;
  if (i < E) atomicAdd(&deg[dst[i]], 1);
}

__global__ void scan1(const int* __restrict__ deg, int* __restrict__ offs,
                      int* __restrict__ bsums, int N) {
  __shared__ int tmp[256];
  const int tid = threadIdx.x;
  const int i = blockIdx.x * 256 + tid;
  int v = (i < N) ? deg[i] : 0;
  tmp[tid] = v;
  __syncthreads();
  for (int d = 1; d < 256; d <<= 1) {
    int t = (tid >= d) ? tmp[tid - d] : 0;
    __syncthreads();
    tmp[tid] += t;
    __syncthreads();
  }
  if (i < N) offs[i] = tmp[tid] - v;
  if (tid == 255) bsums[blockIdx.x] = tmp[255];
}

__global__ void scan2(int* __restrict__ bsums, int nb) {
  __shared__ int tmp[256];
  const int tid = threadIdx.x;
  int v = (tid < nb) ? bsums[tid] : 0;
  tmp[tid] = v;
  __syncthreads();
  for (int d = 1; d < 256; d <<= 1) {
    int t = (tid >= d) ? tmp[tid - d] : 0;
    __syncthreads();
    tmp[tid] += t;
    __syncthreads();
  }
  if (tid < nb) bsums[tid] = tmp[tid] - v;
}

// adds block offsets, finalizes offs, and initializes cursor = offs
__global__ void scan3(int* __restrict__ offs, const int* __restrict__ bsums,
                      int* __restrict__ cursor, int N, int E) {
  const int i = blockIdx.x * 256 + threadIdx.x;
  if (i < N) {
    const int v = offs[i] + bsums[blockIdx.x];
    offs[i] = v;
    cursor[i] = v;
  }
  if (i == 0) offs[N] = E;
}

__global__ void scatter_kernel(const int* __restrict__ src, const int* __restrict__ dst,
                               int* __restrict__ cursor, int* __restrict__ csr_src, int E) {
  int i = blockIdx.x * blockDim.x + threadIdx.x;
  if (i >= E) return;
  int pos = atomicAdd(&cursor[dst[i]], 1);
  csr_src[pos] = src[i];
}

// ---------------- alpha: 16-lane group per dst node (4 nodes/wave); abuf bf16 ----------------
template <int H>
__global__ void alpha16(const int* __restrict__ offs, const int* __restrict__ csr_src,
                        const float* __restrict__ el, const float* __restrict__ er,
                        unsigned short* __restrict__ abuf, int N) {
  const int w = (int)((blockIdx.x * (size_t)blockDim.x + threadIdx.x) >> 6);
  const int lane = threadIdx.x & 63;
  const int g = lane >> 4, q = lane & 15;
  const int node = w * 4 + g;
  int beg = 0, end = 0;
  float erh[H];
#pragma unroll
  for (int h = 0; h < H; ++h) erh[h] = 0.f;
  if (node < N) {
    beg = offs[node]; end = offs[node + 1];
    if constexpr (H == 4) {
      float4 t = *reinterpret_cast<const float4*>(&er[(size_t)node * 4]);
      erh[0] = t.x; erh[1] = t.y; erh[2] = t.z; erh[3] = t.w;
    } else {
      erh[0] = er[node];
    }
  }
  float m[H], s[H];
#pragma unroll
  for (int h = 0; h < H; ++h) { m[h] = -INFINITY; s[h] = 0.f; }
  for (int i0 = beg; i0 < end; i0 += 16) {
    const int i = i0 + q;
    const bool valid = i < end;
    const int sn = valid ? csr_src[i] : 0;
    float e[H];
    if constexpr (H == 4) {
      float4 v = *reinterpret_cast<const float4*>(&el[(size_t)sn * 4]);
      e[0] = v.x + erh[0]; e[1] = v.y + erh[1]; e[2] = v.z + erh[2]; e[3] = v.w + erh[3];
    } else {
      e[0] = el[sn] + erh[0];
    }
#pragma unroll
    for (int h = 0; h < H; ++h) {
      e[h] = e[h] > 0.f ? e[h] : NEG_SLOPE * e[h];
      if (!valid) e[h] = -INFINITY;
      float cm = e[h];
#pragma unroll
      for (int off = 1; off < 16; off <<= 1) cm = fmaxf(cm, __shfl_xor(cm, off));
      const float nm = fmaxf(m[h], cm);
      float cs = __expf(e[h] - nm);
#pragma unroll
      for (int off = 1; off < 16; off <<= 1) cs += __shfl_xor(cs, off);
      s[h] = s[h] * __expf(m[h] - nm) + cs;
      m[h] = nm;
    }
  }
  float inv[H];
#pragma unroll
  for (int h = 0; h < H; ++h) inv[h] = 1.f / fmaxf(s[h], 1e-9f);
  for (int i0 = beg; i0 < end; i0 += 16) {
    const int i = i0 + q;
    if (i < end) {
      const int sn = csr_src[i];
      float e[H];
      if constexpr (H == 4) {
        float4 v = *reinterpret_cast<const float4*>(&el[(size_t)sn * 4]);
        e[0] = v.x + erh[0]; e[1] = v.y + erh[1]; e[2] = v.z + erh[2]; e[3] = v.w + erh[3];
      } else {
        e[0] = el[sn] + erh[0];
      }
#pragma unroll
      for (int h = 0; h < H; ++h) {
        e[h] = e[h] > 0.f ? e[h] : NEG_SLOPE * e[h];
        e[h] = __expf(e[h] - m[h]) * inv[h];
      }
      if constexpr (H == 4) {
        ushort4 o;
        o.x = f2bf(e[0]); o.y = f2bf(e[1]); o.z = f2bf(e[2]); o.w = f2bf(e[3]);
        *reinterpret_cast<ushort4*>(&abuf[(size_t)i * 4]) = o;
      } else {
        abuf[i] = f2bf(e[0]);
      }
    }
  }
}

// ---------------- aggregate H=4: one wave/node, HEAD-INTERLEAVED ushort4 gather, 8-edge unroll ----------------
__global__ void aggregate_h4(const int* __restrict__ offs, const int* __restrict__ csr_src,
                             const ushort4* __restrict__ feat4, const ushort4* __restrict__ abuf4,
                             const float* __restrict__ bias, ushort4* __restrict__ out4, int N) {
  const int node = (int)((blockIdx.x * (size_t)blockDim.x + threadIdx.x) >> 6);
  const int lane = threadIdx.x & 63;
  if (node >= N) return;
  const int beg = offs[node], end = offs[node + 1];
  float a0 = 0.f, a1 = 0.f, a2 = 0.f, a3 = 0.f;
  int i = beg;
  for (; i + 7 < end; i += 8) {
    int sn[8]; ushort4 w[8]; ushort4 uv[8];
#pragma unroll
    for (int u = 0; u < 8; ++u) sn[u] = csr_src[i + u];
#pragma unroll
    for (int u = 0; u < 8; ++u) w[u] = abuf4[i + u];
#pragma unroll
    for (int u = 0; u < 8; ++u) uv[u] = feat4[(size_t)sn[u] * 64 + lane];
#pragma unroll
    for (int u = 0; u < 8; ++u) {
      a0 = fmaf(bf2f(w[u].x), bf2f(uv[u].x), a0);
      a1 = fmaf(bf2f(w[u].y), bf2f(uv[u].y), a1);
      a2 = fmaf(bf2f(w[u].z), bf2f(uv[u].z), a2);
      a3 = fmaf(bf2f(w[u].w), bf2f(uv[u].w), a3);
    }
  }
  for (; i < end; ++i) {
    const int sn = csr_src[i];
    const ushort4 w = abuf4[i];
    const ushort4 uv = feat4[(size_t)sn * 64 + lane];
    a0 = fmaf(bf2f(w.x), bf2f(uv.x), a0);
    a1 = fmaf(bf2f(w.y), bf2f(uv.y), a1);
    a2 = fmaf(bf2f(w.z), bf2f(uv.z), a2);
    a3 = fmaf(bf2f(w.w), bf2f(uv.w), a3);
  }
  const float o0 = a0 + bias[lane];
  const float o1 = a1 + bias[64 + lane];
  const float o2 = a2 + bias[128 + lane];
  const float o3 = a3 + bias[192 + lane];
  ushort4 ov;
  ov.x = f2bf(o0); ov.y = f2bf(o1); ov.z = f2bf(o2); ov.w = f2bf(o3);
  out4[(size_t)node * 64 + lane] = ov;
}

// ---------------- aggregate H=1: 16-lane groups, 4 edges/iter ----------------
__global__ void aggregate1(const int* __restrict__ offs, const int* __restrict__ csr_src,
                           const unsigned short* __restrict__ featH, const unsigned short* __restrict__ abuf,
                           const float* __restrict__ bias, float* __restrict__ outf, int N) {
  const int wid = (int)((blockIdx.x * (size_t)blockDim.x + threadIdx.x) >> 6);
  const int lane = threadIdx.x & 63;
  if (wid >= N) return;
  const int beg = offs[wid], end = offs[wid + 1];
  const int g = lane >> 4, q = lane & 15;
  float4 acc = make_float4(0.f, 0.f, 0.f, 0.f);
  for (int i0 = beg; i0 < end; i0 += 4) {
    const int e = i0 + g;
    if (e < end) {
      const int sn = csr_src[e];
      const float a = bf2f(abuf[e]);
      const ushort4 u = *reinterpret_cast<const ushort4*>(&featH[(size_t)sn * 64 + q * 4]);
      acc.x = fmaf(a, bf2f(u.x), acc.x);
      acc.y = fmaf(a, bf2f(u.y), acc.y);
      acc.z = fmaf(a, bf2f(u.z), acc.z);
      acc.w = fmaf(a, bf2f(u.w), acc.w);
    }
  }
#pragma unroll
  for (int off = 16; off <= 32; off <<= 1) {
    acc.x += __shfl_xor(acc.x, off);
    acc.y += __shfl_xor(acc.y, off);
    acc.z += __shfl_xor(acc.z, off);
    acc.w += __shfl_xor(acc.w, off);
  }
  if (lane < 16) {
    const float4 b4 = *reinterpret_cast<const float4*>(&bias[q * 4]);
    float4 o = make_float4(acc.x + b4.x, acc.y + b4.y, acc.z + b4.z, acc.w + b4.w);
    *reinterpret_cast<float4*>(&outf[(size_t)wid * 64 + q * 4]) = o;
  }
}

// ---------------- tail: ids as float ----------------
__global__ void copy_ids(const int* __restrict__ ids, float* __restrict__ out, int n) {
  int i = blockIdx.x * blockDim.x + threadIdx.x;
  if (i < n) out[i] = (float)ids[i];
}

extern "C" void kernel_launch(void* const* d_in, const int* in_sizes, int n_in,
                              void* d_out, int out_size, void* d_ws, size_t ws_size,
                              hipStream_t stream) {
  const float* h   = (const float*)d_in[0];
  const int* src   = (const int*)d_in[1];
  const int* dst   = (const int*)d_in[2];
  const int* ids   = (const int*)d_in[3];
  const float* W0  = (const float*)d_in[4];
  const float* al0 = (const float*)d_in[5];
  const float* ar0 = (const float*)d_in[6];
  const float* b0  = (const float*)d_in[7];
  const float* W1  = (const float*)d_in[8];
  const float* al1 = (const float*)d_in[9];
  const float* ar1 = (const float*)d_in[10];
  const float* b1  = (const float*)d_in[11];
  const float* W2  = (const float*)d_in[12];
  const float* al2 = (const float*)d_in[13];
  const float* ar2 = (const float*)d_in[14];
  const float* b2  = (const float*)d_in[15];

  const int Din = 256, HF = 256, F2 = 64;
  const int N = in_sizes[0] / Din;        // 50000
  const int E = in_sizes[1];              // 800000
  const int NIDS = in_sizes[3];           // 1024

  // workspace layout (16B-aligned chunks)
  char* p = (char*)d_ws;
  unsigned short* Chi = (unsigned short*)p; p += (size_t)N * 256 * 2;  // feat bf16 (interleaved for H=4)
  unsigned short* Ahi = (unsigned short*)p; p += (size_t)N * 256 * 2;  // GEMM input (bf16)
  unsigned short* W0hi = (unsigned short*)p; p += (size_t)HF * Din * 2;
  unsigned short* W0lo = (unsigned short*)p; p += (size_t)HF * Din * 2;
  unsigned short* W1hi = (unsigned short*)p; p += (size_t)HF * HF * 2;
  unsigned short* W1lo = (unsigned short*)p; p += (size_t)HF * HF * 2;
  unsigned short* W2hi = (unsigned short*)p; p += (size_t)F2 * HF * 2;
  unsigned short* W2lo = (unsigned short*)p; p += (size_t)F2 * HF * 2;
  float* el   = (float*)p;             p += (size_t)N * 4 * 4;
  float* er   = (float*)p;             p += (size_t)N * 4 * 4;
  unsigned short* abuf = (unsigned short*)p; p += (size_t)E * 4 * 2;   // alpha bf16
  int* deg    = (int*)p;               p += (size_t)N * 4;             // also cursor
  int* offs   = (int*)p;               p += (size_t)(N + 16) * 4;
  int* bsums  = (int*)p;               p += 256 * 4;
  int* csr_src = (int*)p;              p += (size_t)E * 4;

  float* outp = (float*)d_out;
  dim3 blk(256);
  const int nb = cdiv(N, 256);
  const int nwAlpha = cdiv(cdiv(N, 4) * 64, 256);

  // ---------------- weight splits (one launch) ----------------
  splitT_all<<<cdiv(256 * 256 * 2 + 256 * 64, 256), blk, 0, stream>>>(
      W0, W0hi, W0lo, W1, W1hi, W1lo, W2, W2hi, W2lo);

  // ---------------- CSR build (shared by all 3 layers) ----------------
  hipMemsetAsync(deg, 0, (size_t)N * 4, stream);
  hist_kernel<<<cdiv(E, 256), blk, 0, stream>>>(dst, deg, E);
  scan1<<<nb, blk, 0, stream>>>(deg, offs, bsums, N);
  scan2<<<1, blk, 0, stream>>>(bsums, nb);
  scan3<<<nb, blk, 0, stream>>>(offs, bsums, deg, N, E);   // deg becomes cursor
  scatter_kernel<<<cdiv(E, 256), blk, 0, stream>>>(src, dst, deg, csr_src, E);

  // ---------------- layer 0 (H=4): h(f32) -> Chi(interleaved) -> Ahi(interleaved) ----------------
  {
    dim3 g(cdiv(N, 128), HF / 128);
    gemm_split<4, true><<<g, blk, 0, stream>>>(nullptr, h, W0hi, W0lo, Chi, al0, ar0, el, er, 4, N, Din, HF);
    alpha16<4><<<nwAlpha, blk, 0, stream>>>(offs, csr_src, el, er, abuf, N);
    aggregate_h4<<<cdiv(N * 64, 256), blk, 0, stream>>>(offs, csr_src, (const ushort4*)Chi,
                                                        (const ushort4*)abuf, b0, (ushort4*)Ahi, N);
  }
  // ---------------- layer 1 (H=4) ----------------
  {
    dim3 g(cdiv(N, 128), HF / 128);
    gemm_split<4, false><<<g, blk, 0, stream>>>(Ahi, nullptr, W1hi, W1lo, Chi, al1, ar1, el, er, 4, N, HF, HF);
    alpha16<4><<<nwAlpha, blk, 0, stream>>>(offs, csr_src, el, er, abuf, N);
    aggregate_h4<<<cdiv(N * 64, 256), blk, 0, stream>>>(offs, csr_src, (const ushort4*)Chi,
                                                        (const ushort4*)abuf, b1, (ushort4*)Ahi, N);
  }
  // ---------------- layer 2 (H=1): -> d_out (standard layout) ----------------
  {
    dim3 g(cdiv(N, 128), 1);
    gemm_split<2, false><<<g, blk, 0, stream>>>(Ahi, nullptr, W2hi, W2lo, Chi, al2, ar2, el, er, 1, N, HF, F2);
    alpha16<1><<<nwAlpha, blk, 0, stream>>>(offs, csr_src, el, er, abuf, N);
    aggregate1<<<cdiv(N * 64, 256), blk, 0, stream>>>(offs, csr_src, Chi, abuf, b2, outp, N);
  }
  // ---------------- tail ids ----------------
  copy_ids<<<cdiv(NIDS, 256), blk, 0, stream>>>(ids, outp + (size_t)N * F2, NIDS);
}